// Round 3
// baseline (183.916 us; speedup 1.0000x reference)
//
#include <hip/hip_runtime.h>
#include <math.h>

#define B_ 4
#define S_ 4096
#define H_ 1024
#define NH 16
#define DH 64
#define CTX 128
#define CSTART (S_ - CTX)   // 3968
#define KDIM 1024

typedef __attribute__((ext_vector_type(8))) short short8;
typedef __attribute__((ext_vector_type(4))) float floatx4;
typedef unsigned short ushort_t;

__device__ inline unsigned short f2bf(float x) {
    union { float f; unsigned u; } v; v.f = x;
    unsigned r = v.u + 0x7fffu + ((v.u >> 16) & 1u);   // RNE
    return (unsigned short)(r >> 16);
}

__device__ inline float bf2f(ushort_t u) {
    union { unsigned u; float f; } v; v.u = ((unsigned)u) << 16; return v.f;
}

__device__ inline uint4 pack8(float4 a, float4 b) {
    union { unsigned short us[8]; uint4 u4; } p;
    p.us[0]=f2bf(a.x); p.us[1]=f2bf(a.y); p.us[2]=f2bf(a.z); p.us[3]=f2bf(a.w);
    p.us[4]=f2bf(b.x); p.us[5]=f2bf(b.y); p.us[6]=f2bf(b.z); p.us[7]=f2bf(b.w);
    return p.u4;
}

#define GLOAD_LDS16(g, l) \
    __builtin_amdgcn_global_load_lds((__attribute__((address_space(1))) const void*)(g), \
                                     (__attribute__((address_space(3))) void*)(l), 16, 0, 0)

// =======================================================================
// K1: fused QKV-projection + attention. One block per (b, h, half).
// GEMM: C[128 ctx rows][192] = Xb(128x1024,bf16) @ [Wq_h;Wk_h;Wv_h]^T
//   acc[2][12] per wave (wave w owns rows w*32..w*32+31, all 192 cols).
// C written directly into the verified attn LDS buffers, then the
// verified attention body runs unchanged.
// =======================================================================
__global__ __launch_bounds__(256, 1) void qkva(const float* __restrict__ in,
                                               const int* __restrict__ amask,
                                               const float* __restrict__ Wq,
                                               const float* __restrict__ Wk,
                                               const float* __restrict__ Wv,
                                               ushort_t* __restrict__ AO) {
    __shared__ __align__(16) char smem[87040];
    ushort_t* As = (ushort_t*)smem;                  // [128][64] bf16
    ushort_t* Bs = (ushort_t*)(smem + 16384);        // [192][64] bf16
    char* ar = smem + 40960;                         // attn region (45824 B used)
    ushort_t* Qs   = (ushort_t*)(ar);                // [64][72]
    ushort_t* Ksh  = (ushort_t*)(ar + 9216);         // [128][72]
    ushort_t* Pb   = (ushort_t*)(ar);                // overlay [64][136]
    float*    linv = (float*)(ar + 27648);           // [64]
    int*      amk  = (int*)(ar + 27904);             // [128]
    ushort_t* Vt   = (ushort_t*)(ar + 28416);        // [64][136]

    int bid = blockIdx.x, tid = threadIdx.x;
    int b = bid >> 5, h = (bid >> 1) & 15, half = bid & 1;
    int lane = tid & 63, w = tid >> 6;
    int fm = lane & 15, q = lane >> 4;

    if (tid < 128) amk[tid] = amask[b * S_ + CSTART + tid];

    // ---- staging coordinates ----
    int rA = tid >> 1, cA0 = (tid & 1) * 4, sA = rA & 7;   // A: 4 chunks of 8
    int rB = tid >> 2, cB0 = (tid & 3) * 2, sB = rB & 7;   // B: 2 chunks x 3 mats
    const float* gA  = in + ((size_t)b * S_ + CSTART + rA) * H_ + cA0 * 8;
    const float* gBq = Wq + (size_t)(h * 64 + rB) * 1024 + cB0 * 8;
    const float* gBk = Wk + (size_t)(h * 64 + rB) * 1024 + cB0 * 8;
    const float* gBv = Wv + (size_t)(h * 64 + rB) * 1024 + cB0 * 8;
    ushort_t* wA = As + rA * 64;
    ushort_t* wB = Bs + rB * 64;

    floatx4 acc[2][12] = {};
    float4 la[8], lb[12];
#define LOADALL(k) do { \
        _Pragma("unroll") \
        for (int cc = 0; cc < 4; cc++) { \
            la[2*cc]   = *(const float4*)(gA + (k) + cc * 8); \
            la[2*cc+1] = *(const float4*)(gA + (k) + cc * 8 + 4); \
        } \
        _Pragma("unroll") \
        for (int cc = 0; cc < 2; cc++) { \
            lb[2*cc]     = *(const float4*)(gBq + (k) + cc * 8); \
            lb[2*cc+1]   = *(const float4*)(gBq + (k) + cc * 8 + 4); \
            lb[4+2*cc]   = *(const float4*)(gBk + (k) + cc * 8); \
            lb[4+2*cc+1] = *(const float4*)(gBk + (k) + cc * 8 + 4); \
            lb[8+2*cc]   = *(const float4*)(gBv + (k) + cc * 8); \
            lb[8+2*cc+1] = *(const float4*)(gBv + (k) + cc * 8 + 4); \
        } } while (0)

    LOADALL(0);
    for (int k0 = 0; k0 < 1024; k0 += 64) {
        uint4 pa[4], pb[6];
        #pragma unroll
        for (int cc = 0; cc < 4; cc++) pa[cc] = pack8(la[2*cc], la[2*cc+1]);
        #pragma unroll
        for (int m = 0; m < 3; m++)
            #pragma unroll
            for (int cc = 0; cc < 2; cc++)
                pb[m*2+cc] = pack8(lb[m*4+2*cc], lb[m*4+2*cc+1]);
        if (k0) __syncthreads();          // prior MFMA reads done before overwrite
        #pragma unroll
        for (int cc = 0; cc < 4; cc++)
            *(uint4*)(wA + ((cA0 + cc) ^ sA) * 8) = pa[cc];
        #pragma unroll
        for (int m = 0; m < 3; m++)
            #pragma unroll
            for (int cc = 0; cc < 2; cc++)
                *(uint4*)(wB + m * 4096 + ((cB0 + cc) ^ sB) * 8) = pb[m*2+cc];
        __syncthreads();
        if (k0 + 64 < 1024) LOADALL(k0 + 64);   // overlap next loads with MFMA
        #pragma unroll
        for (int kb = 0; kb < 2; kb++) {
            short8 af[2];
            #pragma unroll
            for (int i = 0; i < 2; i++) {
                int m = w * 32 + i * 16 + fm;
                af[i] = *(const short8*)(As + m * 64 + (((kb * 4 + q) ^ (m & 7)) * 8));
            }
            #pragma unroll
            for (int j = 0; j < 12; j++) {
                int n = j * 16 + fm;
                short8 bfr = *(const short8*)(Bs + n * 64 + (((kb * 4 + q) ^ (n & 7)) * 8));
                acc[0][j] = __builtin_amdgcn_mfma_f32_16x16x32_bf16(af[0], bfr, acc[0][j], 0, 0, 0);
                acc[1][j] = __builtin_amdgcn_mfma_f32_16x16x32_bf16(af[1], bfr, acc[1][j], 0, 0, 0);
            }
        }
    }
#undef LOADALL

    // ---- C -> attn LDS buffers ----
    // C layout per lane: row = w*32 + i*16 + q*4 + t, col = j*16 + fm.
    // cols 0..63 = Q dims, 64..127 = K dims, 128..191 = V dims.
    bool qown = ((w >> 1) == half);
    #pragma unroll
    for (int i = 0; i < 2; i++) {
        int rbase = w * 32 + i * 16 + q * 4;
        if (qown) {
            #pragma unroll
            for (int j = 0; j < 4; j++)
                #pragma unroll
                for (int t = 0; t < 4; t++)
                    Qs[((rbase & 63) + t) * 72 + j * 16 + fm] = f2bf(acc[i][j][t]);
        }
        #pragma unroll
        for (int j = 4; j < 8; j++)
            #pragma unroll
            for (int t = 0; t < 4; t++)
                Ksh[(rbase + t) * 72 + (j - 4) * 16 + fm] = f2bf(acc[i][j][t]);
        #pragma unroll
        for (int j = 8; j < 12; j++) {
            union { unsigned short us[4]; uint2 u2; } pk;
            #pragma unroll
            for (int t = 0; t < 4; t++) pk.us[t] = f2bf(acc[i][j][t]);
            *(uint2*)(Vt + ((j - 8) * 16 + fm) * 136 + rbase) = pk.u2;   // Vt[d][ctx]
        }
    }
    __syncthreads();

    // ---- verified attention body ----
    int qt = half * 4 + w;
    int lr0 = w * 16;
    int quad = q;

    short8 afq[2];
    #pragma unroll
    for (int kb = 0; kb < 2; kb++)
        afq[kb] = *(const short8*)(Qs + (lr0 + fm) * 72 + kb * 32 + quad * 8);
    floatx4 sc[8] = {};
    for (int ct = 0; ct <= qt; ct++) {
        #pragma unroll
        for (int kb = 0; kb < 2; kb++) {
            short8 bfr = *(const short8*)(Ksh + (ct * 16 + fm) * 72 + kb * 32 + quad * 8);
            sc[ct] = __builtin_amdgcn_mfma_f32_16x16x32_bf16(afq[kb], bfr, sc[ct], 0, 0, 0);
        }
    }
    int myamk[8];
    #pragma unroll
    for (int ct = 0; ct < 8; ct++) myamk[ct] = amk[ct * 16 + fm];
    float ls[4];
    #pragma unroll
    for (int t = 0; t < 4; t++) {
        int row = qt * 16 + quad * 4 + t;
        float m = -INFINITY;
        #pragma unroll
        for (int ct = 0; ct < 8; ct++) {
            int col = ct * 16 + fm;
            float s = sc[ct][t] * 0.125f;
            bool valid = (ct <= qt) && (col <= row) && (myamk[ct] != 0);
            if (valid) m = fmaxf(m, s);
        }
        #pragma unroll
        for (int off = 8; off >= 1; off >>= 1) m = fmaxf(m, __shfl_xor(m, off, 64));
        float l = 0.f;
        #pragma unroll
        for (int ct = 0; ct < 8; ct++) {
            int col = ct * 16 + fm;
            float s = sc[ct][t] * 0.125f;
            bool valid = (ct <= qt) && (col <= row) && (myamk[ct] != 0);
            float p = valid ? __expf(s - m) : 0.f;
            sc[ct][t] = p;
            l += p;
        }
        #pragma unroll
        for (int off = 8; off >= 1; off >>= 1) l += __shfl_xor(l, off, 64);
        ls[t] = l;
    }
    __syncthreads();   // QK^T LDS reads done; Pb overlays Qs/Ksh
    #pragma unroll
    for (int t = 0; t < 4; t++) {
        int lrow = lr0 + quad * 4 + t;
        #pragma unroll
        for (int ct = 0; ct < 8; ct++)
            Pb[lrow * 136 + ct * 16 + fm] = f2bf(sc[ct][t]);
        if (fm == 0) linv[lrow] = 1.f / ls[t];
    }
    int kmax = (qt >> 1) + 1;
    floatx4 oacc[4] = {};
    for (int kb = 0; kb < kmax; kb++) {
        short8 paf = *(const short8*)(Pb + (lr0 + fm) * 136 + kb * 32 + quad * 8);
        #pragma unroll
        for (int dt = 0; dt < 4; dt++) {
            short8 vbf = *(const short8*)(Vt + (dt * 16 + fm) * 136 + kb * 32 + quad * 8);
            oacc[dt] = __builtin_amdgcn_mfma_f32_16x16x32_bf16(paf, vbf, oacc[dt], 0, 0, 0);
        }
    }
    #pragma unroll
    for (int t = 0; t < 4; t++) {
        int lrow = lr0 + quad * 4 + t;
        int grow = qt * 16 + quad * 4 + t;
        float inv = linv[lrow];
        #pragma unroll
        for (int dt = 0; dt < 4; dt++)
            AO[(size_t)(b * CTX + grow) * H_ + h * 64 + dt * 16 + fm] = f2bf(oacc[dt][t] * inv);
    }
}

// =======================================================================
// K2 (verified, unchanged): blocks 0..127 O-GEMM direct-store to out rows
// CSTART..; blocks 128..639 redundantly compute the broadcast row slice
// and stream rows 0..CSTART-1.
// =======================================================================
__global__ __launch_bounds__(256) void ogemm_bcast(const ushort_t* __restrict__ AObf,
                                                   const float* __restrict__ Wo,
                                                   float* __restrict__ out) {
    __shared__ __align__(16) char smem[16384];
    int bid = blockIdx.x;
    int tid = threadIdx.x;

    if (bid < 128) {
        ushort_t (*As)[64] = (ushort_t(*)[64])smem;
        ushort_t (*Bs)[64] = (ushort_t(*)[64])(smem + 8192);
        int x = bid % 16, y = bid / 16;
        int m0 = y * 64, n0 = x * 64;
        int lane = tid & 63, w = tid >> 6;
        int r0 = tid >> 3, g0 = (tid & 7) ^ (r0 & 7);
        int r1 = r0 + 32,  g1 = (tid & 7) ^ (r1 & 7);
        const ushort_t* ga0 = AObf + (size_t)(m0 + r0) * KDIM + g0 * 8;
        const ushort_t* ga1 = AObf + (size_t)(m0 + r1) * KDIM + g1 * 8;
        const float*    gb0 = Wo + (size_t)(n0 + r0) * 1024 + g0 * 8;
        const float*    gb1 = Wo + (size_t)(n0 + r1) * 1024 + g1 * 8;
        char* laA0 = smem + tid * 16;
        char* laA1 = smem + tid * 16 + 4096;
        uint4* lsB0 = (uint4*)(smem + 8192 + tid * 16);
        uint4* lsB1 = (uint4*)(smem + 8192 + tid * 16 + 4096);

        int fm = lane & 15, q = lane >> 4;
        int wr = w >> 1, wc = w & 1;
        int ma0 = wr * 32, na0 = wc * 32;
        floatx4 acc[2][2] = {};

        float4 rb0, rb1, rb2, rb3;
#define LOAD_REGS_K3(k) do { \
            rb0 = *(const float4*)(gb0 + (k)); rb1 = *(const float4*)(gb0 + (k) + 4); \
            rb2 = *(const float4*)(gb1 + (k)); rb3 = *(const float4*)(gb1 + (k) + 4); } while (0)

        LOAD_REGS_K3(0);
        for (int k0 = 0; k0 < 1024; k0 += 64) {
            uint4 pb0 = pack8(rb0, rb1), pb1 = pack8(rb2, rb3);
            if (k0) __syncthreads();
            GLOAD_LDS16(ga0 + k0, laA0);
            GLOAD_LDS16(ga1 + k0, laA1);
            *lsB0 = pb0; *lsB1 = pb1;
            __syncthreads();
            if (k0 + 64 < 1024) LOAD_REGS_K3(k0 + 64);
            #pragma unroll
            for (int kb = 0; kb < 2; kb++) {
                short8 af[2], bfr[2];
                #pragma unroll
                for (int t = 0; t < 2; t++) {
                    int m = ma0 + t * 16 + fm;
                    int pa = (kb * 4 + q) ^ (m & 7);
                    af[t] = *(const short8*)(&As[m][pa * 8]);
                    int n = na0 + t * 16 + fm;
                    int pb = (kb * 4 + q) ^ (n & 7);
                    bfr[t] = *(const short8*)(&Bs[n][pb * 8]);
                }
                #pragma unroll
                for (int i = 0; i < 2; i++)
                    #pragma unroll
                    for (int j = 0; j < 2; j++)
                        acc[i][j] = __builtin_amdgcn_mfma_f32_16x16x32_bf16(af[i], bfr[j], acc[i][j], 0, 0, 0);
            }
        }
#undef LOAD_REGS_K3
        #pragma unroll
        for (int i = 0; i < 2; i++)
            #pragma unroll
            for (int j = 0; j < 2; j++) {
                int row = m0 + ma0 + i * 16 + q * 4;
                int col = n0 + na0 + j * 16 + fm;
                #pragma unroll
                for (int t = 0; t < 4; t++) {
                    int rr = row + t;
                    size_t gr = (size_t)((rr >> 7) * S_ + CSTART + (rr & 127));
                    out[gr * 1024 + col] = acc[i][j][t];
                }
            }
    } else {
        float* vals = (float*)smem;            // [64]
        int idx = bid - 128;                   // 0..511
        int c  = idx & 15;
        int b2 = (idx >> 4) & 3;
        int rc = idx >> 6;                     // 0..7 row chunk (496 rows)
        int n0 = c * 64;
        int w = tid >> 6, lane = tid & 63;
        int rsub = lane >> 4, kl = lane & 15;
        const ushort_t* ao = AObf + (size_t)(b2 * 128) * 1024;
        #pragma unroll
        for (int p = 0; p < 4; p++) {
            int rl = p * 16 + w * 4 + rsub;
            const float* wrow = Wo + (size_t)(n0 + rl) * 1024;
            float4 av = {0.f, 0.f, 0.f, 0.f};
            #pragma unroll
            for (int it = 0; it < 16; it++) {
                int k = kl * 4 + it * 64;
                float4 wv = *(const float4*)(wrow + k);
                av.x += wv.x * bf2f(ao[k]);
                av.y += wv.y * bf2f(ao[k + 1]);
                av.z += wv.z * bf2f(ao[k + 2]);
                av.w += wv.w * bf2f(ao[k + 3]);
            }
            float s = av.x + av.y + av.z + av.w;
            #pragma unroll
            for (int off = 1; off < 16; off <<= 1) s += __shfl_xor(s, off, 64);
            if (kl == 0) vals[rl] = s;
        }
        __syncthreads();
        int c4 = tid & 15, ro = tid >> 4;
        float4 v4 = *(const float4*)(vals + c4 * 4);
        size_t gbase = (size_t)b2 * S_ * 1024 + n0 + c4 * 4;
        #pragma unroll
        for (int i = 0; i < 31; i++) {
            int p = rc * 496 + ro + i * 16;
            *(float4*)(out + gbase + (size_t)p * 1024) = v4;
        }
    }
}

extern "C" void kernel_launch(void* const* d_in, const int* in_sizes, int n_in,
                              void* d_out, int out_size, void* d_ws, size_t ws_size,
                              hipStream_t stream) {
    const float* inputs = (const float*)d_in[0];
    const int*   amask  = (const int*)d_in[1];
    const float* Wq     = (const float*)d_in[2];
    const float* Wk     = (const float*)d_in[3];
    const float* Wv     = (const float*)d_in[4];
    const float* Wo     = (const float*)d_in[5];
    float* out = (float*)d_out;

    ushort_t* AObf = (ushort_t*)d_ws;   // 1 MB [512][1024] bf16

    qkva<<<128, 256, 0, stream>>>(inputs, amask, Wq, Wk, Wv, AObf);
    ogemm_bcast<<<640, 256, 0, stream>>>(AObf, Wo, out);
}

// Round 4
// 156.851 us; speedup vs baseline: 1.1726x; 1.1726x over previous
//
#include <hip/hip_runtime.h>
#include <math.h>

#define B_ 4
#define S_ 4096
#define H_ 1024
#define NH 16
#define DH 64
#define CTX 128
#define CSTART (S_ - CTX)   // 3968
#define KDIM 1024

typedef __attribute__((ext_vector_type(8))) short short8;
typedef __attribute__((ext_vector_type(4))) float floatx4;
typedef unsigned short ushort_t;

__device__ inline unsigned short f2bf(float x) {
    union { float f; unsigned u; } v; v.f = x;
    unsigned r = v.u + 0x7fffu + ((v.u >> 16) & 1u);   // RNE
    return (unsigned short)(r >> 16);
}

__device__ inline float bf2f(ushort_t u) {
    union { unsigned u; float f; } v; v.u = ((unsigned)u) << 16; return v.f;
}

__device__ inline uint4 pack8(float4 a, float4 b) {
    union { unsigned short us[8]; uint4 u4; } p;
    p.us[0]=f2bf(a.x); p.us[1]=f2bf(a.y); p.us[2]=f2bf(a.z); p.us[3]=f2bf(a.w);
    p.us[4]=f2bf(b.x); p.us[5]=f2bf(b.y); p.us[6]=f2bf(b.z); p.us[7]=f2bf(b.w);
    return p.u4;
}

#define GLOAD_LDS16(g, l) \
    __builtin_amdgcn_global_load_lds((__attribute__((address_space(1))) const void*)(g), \
                                     (__attribute__((address_space(3))) void*)(l), 16, 0, 0)

// =======================================================================
// K1: QKV GEMM, non-split K=1024, inline fp32->bf16 staging, bf16 output.
// Pqb[512][3072] = Xslice(bf16) @ [Wq|Wk|Wv](bf16)^T
// grid = 384 = 48(n) x 8(m). Same verified 64x64 XOR-swizzled 2-phase
// structure as round 2 (identical LDS image / MFMA read side).
// fp32 accumulate over full K, single f2bf at the end -> same rounding
// points as the round-2 split-K + fp32-partial-add path.
// =======================================================================
__global__ __launch_bounds__(256) void qkv_gemm(const float* __restrict__ in,
                                                const float* __restrict__ Wq,
                                                const float* __restrict__ Wk,
                                                const float* __restrict__ Wv,
                                                ushort_t* __restrict__ Pqb) {
    __shared__ ushort_t As[64][64];
    __shared__ ushort_t Bs[64][64];
    int bid = blockIdx.x;
    int x = bid % 48, y = bid / 48;
    int m0 = y * 64, n0 = x * 64;
    const float* Wsrc = (n0 < 1024) ? Wq : (n0 < 2048) ? Wk : Wv;
    int nrow0 = n0 & 1023;

    int tid = threadIdx.x;
    int lane = tid & 63, w = tid >> 6;
    int r0 = tid >> 3, g0 = (tid & 7) ^ (r0 & 7);
    int r1 = r0 + 32,  g1 = (tid & 7) ^ (r1 & 7);

    int am0 = m0 + r0, am1 = m0 + r1;
    const float* gaA0 = in + (size_t)((am0 >> 7) * S_ + CSTART + (am0 & 127)) * H_ + g0 * 8;
    const float* gaA1 = in + (size_t)((am1 >> 7) * S_ + CSTART + (am1 & 127)) * H_ + g1 * 8;
    const float* gaB0 = Wsrc + (size_t)(nrow0 + r0) * 1024 + g0 * 8;
    const float* gaB1 = Wsrc + (size_t)(nrow0 + r1) * 1024 + g1 * 8;
    uint4* lsA0 = (uint4*)((char*)As + tid * 16);
    uint4* lsA1 = (uint4*)((char*)As + tid * 16 + 4096);
    uint4* lsB0 = (uint4*)((char*)Bs + tid * 16);
    uint4* lsB1 = (uint4*)((char*)Bs + tid * 16 + 4096);

    int fm = lane & 15, q = lane >> 4;
    int wr = w >> 1, wc = w & 1;
    int ma0 = wr * 32, na0 = wc * 32;
    floatx4 acc[2][2] = {};

    float4 ra0, ra1, ra2, ra3, rb0, rb1, rb2, rb3;
#define LOAD_REGS_K1(k) do { \
        ra0 = *(const float4*)(gaA0 + (k));     ra1 = *(const float4*)(gaA0 + (k) + 4); \
        ra2 = *(const float4*)(gaA1 + (k));     ra3 = *(const float4*)(gaA1 + (k) + 4); \
        rb0 = *(const float4*)(gaB0 + (k));     rb1 = *(const float4*)(gaB0 + (k) + 4); \
        rb2 = *(const float4*)(gaB1 + (k));     rb3 = *(const float4*)(gaB1 + (k) + 4); } while (0)

    LOAD_REGS_K1(0);
    for (int k0 = 0; k0 < 1024; k0 += 64) {
        uint4 pa0 = pack8(ra0, ra1), pa1 = pack8(ra2, ra3);
        uint4 pb0 = pack8(rb0, rb1), pb1 = pack8(rb2, rb3);
        if (k0) __syncthreads();          // prior MFMA reads done before overwrite
        *lsA0 = pa0; *lsA1 = pa1; *lsB0 = pb0; *lsB1 = pb1;
        __syncthreads();
        if (k0 + 64 < 1024) LOAD_REGS_K1(k0 + 64);   // overlap with MFMA phase
        #pragma unroll
        for (int kb = 0; kb < 2; kb++) {
            short8 af[2], bfr[2];
            #pragma unroll
            for (int t = 0; t < 2; t++) {
                int m = ma0 + t * 16 + fm;
                int pa = (kb * 4 + q) ^ (m & 7);
                af[t] = *(const short8*)(&As[m][pa * 8]);
                int n = na0 + t * 16 + fm;
                int pb = (kb * 4 + q) ^ (n & 7);
                bfr[t] = *(const short8*)(&Bs[n][pb * 8]);
            }
            #pragma unroll
            for (int i = 0; i < 2; i++)
                #pragma unroll
                for (int j = 0; j < 2; j++)
                    acc[i][j] = __builtin_amdgcn_mfma_f32_16x16x32_bf16(af[i], bfr[j], acc[i][j], 0, 0, 0);
        }
    }
#undef LOAD_REGS_K1
    #pragma unroll
    for (int i = 0; i < 2; i++)
        #pragma unroll
        for (int j = 0; j < 2; j++) {
            int row = m0 + ma0 + i * 16 + q * 4;
            int col = n0 + na0 + j * 16 + fm;
            #pragma unroll
            for (int t = 0; t < 4; t++)
                Pqb[(size_t)(row + t) * 3072 + col] = f2bf(acc[i][j][t]);
        }
}

// =======================================================================
// K2: MFMA attention, staging now straight bf16 copies from Pqb.
// block = (b, h, half); body identical to the verified attention.
// =======================================================================
__global__ __launch_bounds__(256) void attn(const ushort_t* __restrict__ Pqb,  // [512][3072] bf16
                                            const int* __restrict__ amask,
                                            ushort_t* __restrict__ AO) {
    __shared__ __align__(16) char smem[46080];
    ushort_t* Qs   = (ushort_t*)(smem);             // [64][72]
    ushort_t* Ksh  = (ushort_t*)(smem + 9216);      // [128][72]
    ushort_t* Pb   = (ushort_t*)(smem);             // overlay, [64][136]
    float*    linv = (float*)(smem + 27648);        // [64]
    int*      amk  = (int*)(smem + 27904);          // [128]
    ushort_t* Vt   = (ushort_t*)(smem + 28416);     // [64][136]

    int gid = blockIdx.x;
    int b = gid >> 5, h = (gid >> 1) & 15, half = gid & 1;
    int tid = threadIdx.x;
    int cmax = half ? CTX : 64;
    {
        // Q rows: local r -> global q row half*64 + r, 64 bf16 each
        int r = tid >> 2, c0 = (tid & 3) * 16;
        const ushort_t* qsrc = Pqb + (size_t)(b * CTX + half * 64 + r) * 3072 + h * 64 + c0;
        *(uint4*)(Qs + r * 72 + c0)     = *(const uint4*)(qsrc);
        *(uint4*)(Qs + r * 72 + c0 + 8) = *(const uint4*)(qsrc + 8);
        // K rows + V (transposed into Vt[d][ctx])
        for (int idx = tid; idx < cmax * 4; idx += 256) {
            int kr = idx >> 2, kch = idx & 3;
            const ushort_t* kb = Pqb + (size_t)(b * CTX + kr) * 3072 + 1024 + h * 64 + kch * 16;
            *(uint4*)(Ksh + kr * 72 + kch * 16)     = *(const uint4*)(kb);
            *(uint4*)(Ksh + kr * 72 + kch * 16 + 8) = *(const uint4*)(kb + 8);
            const ushort_t* vb = Pqb + (size_t)(b * CTX + kr) * 3072 + 2048 + h * 64 + kch * 16;
            union { uint4 u[2]; ushort_t us[16]; } vv;
            vv.u[0] = *(const uint4*)(vb);
            vv.u[1] = *(const uint4*)(vb + 8);
            #pragma unroll
            for (int i = 0; i < 16; i++)
                Vt[(kch * 16 + i) * 136 + kr] = vv.us[i];
        }
        if (tid < 128) amk[tid] = amask[b * S_ + CSTART + tid];
    }
    __syncthreads();

    int w = tid >> 6, lane = tid & 63;
    int qt = half * 4 + w;
    int lr0 = w * 16;
    int fm = lane & 15, quad = lane >> 4;

    short8 af[2];
    #pragma unroll
    for (int kb = 0; kb < 2; kb++)
        af[kb] = *(const short8*)(Qs + (lr0 + fm) * 72 + kb * 32 + quad * 8);
    floatx4 acc[8] = {};
    for (int ct = 0; ct <= qt; ct++) {
        #pragma unroll
        for (int kb = 0; kb < 2; kb++) {
            short8 bfr = *(const short8*)(Ksh + (ct * 16 + fm) * 72 + kb * 32 + quad * 8);
            acc[ct] = __builtin_amdgcn_mfma_f32_16x16x32_bf16(af[kb], bfr, acc[ct], 0, 0, 0);
        }
    }
    int myamk[8];
    #pragma unroll
    for (int ct = 0; ct < 8; ct++) myamk[ct] = amk[ct * 16 + fm];
    float ls[4];
    #pragma unroll
    for (int t = 0; t < 4; t++) {
        int row = qt * 16 + quad * 4 + t;
        float m = -INFINITY;
        #pragma unroll
        for (int ct = 0; ct < 8; ct++) {
            int col = ct * 16 + fm;
            float s = acc[ct][t] * 0.125f;
            bool valid = (ct <= qt) && (col <= row) && (myamk[ct] != 0);
            if (valid) m = fmaxf(m, s);
        }
        #pragma unroll
        for (int off = 8; off >= 1; off >>= 1) m = fmaxf(m, __shfl_xor(m, off, 64));
        float l = 0.f;
        #pragma unroll
        for (int ct = 0; ct < 8; ct++) {
            int col = ct * 16 + fm;
            float s = acc[ct][t] * 0.125f;
            bool valid = (ct <= qt) && (col <= row) && (myamk[ct] != 0);
            float p = valid ? __expf(s - m) : 0.f;
            acc[ct][t] = p;
            l += p;
        }
        #pragma unroll
        for (int off = 8; off >= 1; off >>= 1) l += __shfl_xor(l, off, 64);
        ls[t] = l;
    }
    __syncthreads();   // QK^T LDS reads done; Pb overlays Qs/Ksh
    #pragma unroll
    for (int t = 0; t < 4; t++) {
        int lrow = lr0 + quad * 4 + t;
        #pragma unroll
        for (int ct = 0; ct < 8; ct++)
            Pb[lrow * 136 + ct * 16 + fm] = f2bf(acc[ct][t]);
        if (fm == 0) linv[lrow] = 1.f / ls[t];
    }
    int kmax = (qt >> 1) + 1;
    floatx4 oacc[4] = {};
    for (int kb = 0; kb < kmax; kb++) {
        short8 paf = *(const short8*)(Pb + (lr0 + fm) * 136 + kb * 32 + quad * 8);
        #pragma unroll
        for (int dt = 0; dt < 4; dt++) {
            short8 vbf = *(const short8*)(Vt + (dt * 16 + fm) * 136 + kb * 32 + quad * 8);
            oacc[dt] = __builtin_amdgcn_mfma_f32_16x16x32_bf16(paf, vbf, oacc[dt], 0, 0, 0);
        }
    }
    #pragma unroll
    for (int t = 0; t < 4; t++) {
        int lrow = lr0 + quad * 4 + t;
        int grow = qt * 16 + quad * 4 + t;
        float inv = linv[lrow];
        #pragma unroll
        for (int dt = 0; dt < 4; dt++)
            AO[(size_t)(b * CTX + grow) * H_ + h * 64 + dt * 16 + fm] = f2bf(oacc[dt][t] * inv);
    }
}

// =======================================================================
// K3 (verified, unchanged from round 2): blocks 0..127 O-GEMM direct-store
// to out rows CSTART..; blocks 128..639 redundantly compute the broadcast
// row slice and stream rows 0..CSTART-1.
// =======================================================================
__global__ __launch_bounds__(256) void ogemm_bcast(const ushort_t* __restrict__ AObf,
                                                   const float* __restrict__ Wo,
                                                   float* __restrict__ out) {
    __shared__ __align__(16) char smem[16384];
    int bid = blockIdx.x;
    int tid = threadIdx.x;

    if (bid < 128) {
        ushort_t (*As)[64] = (ushort_t(*)[64])smem;
        ushort_t (*Bs)[64] = (ushort_t(*)[64])(smem + 8192);
        int x = bid % 16, y = bid / 16;
        int m0 = y * 64, n0 = x * 64;
        int lane = tid & 63, w = tid >> 6;
        int r0 = tid >> 3, g0 = (tid & 7) ^ (r0 & 7);
        int r1 = r0 + 32,  g1 = (tid & 7) ^ (r1 & 7);
        const ushort_t* ga0 = AObf + (size_t)(m0 + r0) * KDIM + g0 * 8;
        const ushort_t* ga1 = AObf + (size_t)(m0 + r1) * KDIM + g1 * 8;
        const float*    gb0 = Wo + (size_t)(n0 + r0) * 1024 + g0 * 8;
        const float*    gb1 = Wo + (size_t)(n0 + r1) * 1024 + g1 * 8;
        char* laA0 = smem + tid * 16;
        char* laA1 = smem + tid * 16 + 4096;
        uint4* lsB0 = (uint4*)(smem + 8192 + tid * 16);
        uint4* lsB1 = (uint4*)(smem + 8192 + tid * 16 + 4096);

        int fm = lane & 15, q = lane >> 4;
        int wr = w >> 1, wc = w & 1;
        int ma0 = wr * 32, na0 = wc * 32;
        floatx4 acc[2][2] = {};

        float4 rb0, rb1, rb2, rb3;
#define LOAD_REGS_K3(k) do { \
            rb0 = *(const float4*)(gb0 + (k)); rb1 = *(const float4*)(gb0 + (k) + 4); \
            rb2 = *(const float4*)(gb1 + (k)); rb3 = *(const float4*)(gb1 + (k) + 4); } while (0)

        LOAD_REGS_K3(0);
        for (int k0 = 0; k0 < 1024; k0 += 64) {
            uint4 pb0 = pack8(rb0, rb1), pb1 = pack8(rb2, rb3);
            if (k0) __syncthreads();
            GLOAD_LDS16(ga0 + k0, laA0);
            GLOAD_LDS16(ga1 + k0, laA1);
            *lsB0 = pb0; *lsB1 = pb1;
            __syncthreads();
            if (k0 + 64 < 1024) LOAD_REGS_K3(k0 + 64);
            #pragma unroll
            for (int kb = 0; kb < 2; kb++) {
                short8 af[2], bfr[2];
                #pragma unroll
                for (int t = 0; t < 2; t++) {
                    int m = ma0 + t * 16 + fm;
                    int pa = (kb * 4 + q) ^ (m & 7);
                    af[t] = *(const short8*)(&As[m][pa * 8]);
                    int n = na0 + t * 16 + fm;
                    int pb = (kb * 4 + q) ^ (n & 7);
                    bfr[t] = *(const short8*)(&Bs[n][pb * 8]);
                }
                #pragma unroll
                for (int i = 0; i < 2; i++)
                    #pragma unroll
                    for (int j = 0; j < 2; j++)
                        acc[i][j] = __builtin_amdgcn_mfma_f32_16x16x32_bf16(af[i], bfr[j], acc[i][j], 0, 0, 0);
            }
        }
#undef LOAD_REGS_K3
        #pragma unroll
        for (int i = 0; i < 2; i++)
            #pragma unroll
            for (int j = 0; j < 2; j++) {
                int row = m0 + ma0 + i * 16 + q * 4;
                int col = n0 + na0 + j * 16 + fm;
                #pragma unroll
                for (int t = 0; t < 4; t++) {
                    int rr = row + t;
                    size_t gr = (size_t)((rr >> 7) * S_ + CSTART + (rr & 127));
                    out[gr * 1024 + col] = acc[i][j][t];
                }
            }
    } else {
        float* vals = (float*)smem;            // [64]
        int idx = bid - 128;                   // 0..511
        int c  = idx & 15;
        int b2 = (idx >> 4) & 3;
        int rc = idx >> 6;                     // 0..7 row chunk (496 rows)
        int n0 = c * 64;
        int w = tid >> 6, lane = tid & 63;
        int rsub = lane >> 4, kl = lane & 15;
        const ushort_t* ao = AObf + (size_t)(b2 * 128) * 1024;
        #pragma unroll
        for (int p = 0; p < 4; p++) {
            int rl = p * 16 + w * 4 + rsub;
            const float* wrow = Wo + (size_t)(n0 + rl) * 1024;
            float4 av = {0.f, 0.f, 0.f, 0.f};
            #pragma unroll
            for (int it = 0; it < 16; it++) {
                int k = kl * 4 + it * 64;
                float4 wv = *(const float4*)(wrow + k);
                av.x += wv.x * bf2f(ao[k]);
                av.y += wv.y * bf2f(ao[k + 1]);
                av.z += wv.z * bf2f(ao[k + 2]);
                av.w += wv.w * bf2f(ao[k + 3]);
            }
            float s = av.x + av.y + av.z + av.w;
            #pragma unroll
            for (int off = 1; off < 16; off <<= 1) s += __shfl_xor(s, off, 64);
            if (kl == 0) vals[rl] = s;
        }
        __syncthreads();
        int c4 = tid & 15, ro = tid >> 4;
        float4 v4 = *(const float4*)(vals + c4 * 4);
        size_t gbase = (size_t)b2 * S_ * 1024 + n0 + c4 * 4;
        #pragma unroll
        for (int i = 0; i < 31; i++) {
            int p = rc * 496 + ro + i * 16;
            *(float4*)(out + gbase + (size_t)p * 1024) = v4;
        }
    }
}

extern "C" void kernel_launch(void* const* d_in, const int* in_sizes, int n_in,
                              void* d_out, int out_size, void* d_ws, size_t ws_size,
                              hipStream_t stream) {
    const float* inputs = (const float*)d_in[0];
    const int*   amask  = (const int*)d_in[1];
    const float* Wq     = (const float*)d_in[2];
    const float* Wk     = (const float*)d_in[3];
    const float* Wv     = (const float*)d_in[4];
    const float* Wo     = (const float*)d_in[5];
    float* out = (float*)d_out;

    char* ws = (char*)d_ws;
    ushort_t* Pqb  = (ushort_t*)(ws);                // 3 MB [512][3072] bf16
    ushort_t* AObf = (ushort_t*)(ws + (4u << 20));   // 1 MB [512][1024] bf16

    qkv_gemm<<<384, 256, 0, stream>>>(inputs, Wq, Wk, Wv, Pqb);
    attn<<<128, 256, 0, stream>>>(Pqb, amask, AObf);
    ogemm_bcast<<<640, 256, 0, stream>>>(AObf, Wo, out);
}